// Round 6
// baseline (377.018 us; speedup 1.0000x reference)
//
#include <hip/hip_runtime.h>
#include <stdint.h>

#define NEUR 1024
#define BM 64
#define THREADS 512
#define H1S 2064   // h1 row stride in bytes (1024*2 + 16 pad -> bank spread, imm-foldable)

typedef short  s16x8  __attribute__((ext_vector_type(8)));
typedef __bf16 bf16x8 __attribute__((ext_vector_type(8)));
typedef float  f32x16 __attribute__((ext_vector_type(16)));

__device__ __forceinline__ unsigned short f2bf(float f){
  unsigned u = __builtin_bit_cast(unsigned, f);
  u += 0x7FFFu + ((u >> 16) & 1u);          // round-to-nearest-even
  return (unsigned short)(u >> 16);
}
__device__ __forceinline__ float bf2f(unsigned short h){
  unsigned u = ((unsigned)h) << 16;
  return __builtin_bit_cast(float, u);
}
__device__ __forceinline__ f32x16 mfma32(bf16x8 a, bf16x8 b, f32x16 c){
  return __builtin_amdgcn_mfma_f32_32x32x16_bf16(a, b, c, 0, 0, 0);
}
__device__ __forceinline__ f32x16 zero16(){
  f32x16 v;
#pragma unroll
  for (int r = 0; r < 16; ++r) v[r] = 0.f;
  return v;
}
__device__ __forceinline__ bf16x8 ld16(const void* p){
  return __builtin_bit_cast(bf16x8, *reinterpret_cast<const s16x8*>(p));
}

// Pre-swizzle weights into MFMA-fragment order so GEMM loads are coalesced.
// w2opt[((nt*64 + ks)*64 + l)*8 + j] = bf16(W2[nt*32 + (l&31)][ks*16 + (l>>5)*8 + j])
// w1opt[((nt*2  + ks)*64 + l)*8 + j] = bf16(W1 padded to K=32, same fragment map)
__global__ void prep_kernel(const float* __restrict__ W1, const float* __restrict__ W2,
                            unsigned short* __restrict__ w2opt, unsigned short* __restrict__ w1opt){
  const int nchunks = NEUR * 128;            // 8-float chunks of W2 (read-coalesced)
  const int total = nchunks + 4096;          // + w1opt lane-blocks
  for (int i = blockIdx.x*blockDim.x + threadIdx.x; i < total; i += gridDim.x*blockDim.x){
    if (i < nchunks){
      const int col = i >> 7, c8 = i & 127;
      const float* src = W2 + (size_t)col*NEUR + c8*8;
      const int ks = c8 >> 1, lf = c8 & 1, lane = lf*32 + (col & 31), nt = col >> 5;
      unsigned short* dst = w2opt + (((size_t)(nt*64 + ks)*64 + lane) * 8);
#pragma unroll
      for (int j = 0; j < 8; ++j) dst[j] = f2bf(src[j]);
    } else {
      const int o = i - nchunks;             // ((nt*2+ks)*64 + lane)
      const int nt = o >> 7, ks = (o >> 6) & 1, lane = o & 63;
      const int col = nt*32 + (lane & 31);
      unsigned short* dst = w1opt + (size_t)o * 8;
#pragma unroll
      for (int j = 0; j < 8; ++j){
        const int k = ks*16 + (lane >> 5)*8 + j;
        dst[j] = (k < 10) ? f2bf(W1[col*10 + k]) : (unsigned short)0;
      }
    }
  }
}

template<bool BFWS>
__global__ __launch_bounds__(THREADS, 2) void mlp_kernel(
    const float* __restrict__ x,
    const float* __restrict__ Wx, const float* __restrict__ bxp,
    const float* __restrict__ Wu, const float* __restrict__ bup,
    const float* __restrict__ W1, const float* __restrict__ b1,
    const float* __restrict__ W2f, const float* __restrict__ b2,
    const float* __restrict__ W3, const float* __restrict__ b3,
    const unsigned short* __restrict__ w2opt, const unsigned short* __restrict__ w1opt,
    float* __restrict__ out)
{
  extern __shared__ char smem[];
  unsigned short* l1p = (unsigned short*)smem;   // [64][40] bf16 (5120 B, padded stride)
  char* h1            = smem + 5120;             // 64 rows x 2064 B (padded), bf16

  const int tid = threadIdx.x;
  const int l   = tid & 63;
  const int wid = tid >> 6;                      // 8 waves
  const int l31 = l & 31;
  const int lh  = l >> 5;
  const long rbase = (long)blockIdx.x * BM;

  // ---- 1. stage x tile (64*25 f32), overlaying h1 region
  float* xs = (float*)h1;
  for (int i = tid; i < BM*25; i += THREADS) xs[i] = x[rbase*25 + i];
  __syncthreads();

  // ---- 2. l1 features (f32 exact), bf16-pad to K=32 in l1p
  if (tid < BM){
    const float* xr = xs + tid*25;
    float l1v[10];
#pragma unroll
    for (int g = 0; g < 3; ++g)
#pragma unroll
      for (int o = 0; o < 2; ++o){
        float s = bxp[o];
#pragma unroll
        for (int i = 0; i < 5; ++i) s += xr[g + 3*i] * Wx[o*5 + i];
        l1v[g*2 + o] = fmaxf(s, 0.f);
      }
#pragma unroll
    for (int g = 0; g < 2; ++g)
#pragma unroll
      for (int o = 0; o < 2; ++o){
        float s = bup[o];
#pragma unroll
        for (int i = 0; i < 5; ++i) s += xr[15 + g + 2*i] * Wu[o*5 + i];
        l1v[6 + g*2 + o] = fmaxf(s, 0.f);
      }
    unsigned short* dst = l1p + tid*40;
#pragma unroll
    for (int i = 0; i < 10; ++i) dst[i] = f2bf(l1v[i]);
#pragma unroll
    for (int i = 10; i < 32; ++i) dst[i] = 0;
  }
  __syncthreads();

  // ---- 3. GEMM1: h1[64][wid*128 .. +128) = relu(l1 @ W1^T + b1)
  {
    f32x16 c[2][4];
#pragma unroll
    for (int mt = 0; mt < 2; ++mt)
#pragma unroll
      for (int nt = 0; nt < 4; ++nt) c[mt][nt] = zero16();

#pragma unroll
    for (int ks = 0; ks < 2; ++ks){
      bf16x8 a0 = ld16(smem + l31*80 + ks*32 + lh*16);
      bf16x8 a1 = ld16(smem + (32 + l31)*80 + ks*32 + lh*16);
      bf16x8 b[4];
#pragma unroll
      for (int nt = 0; nt < 4; ++nt){
        if constexpr (BFWS){
          b[nt] = ld16(w1opt + (((size_t)((wid*4 + nt)*2 + ks)*64 + l) * 8));
        } else {
          const int col = wid*128 + nt*32 + l31;
          s16x8 raw;
#pragma unroll
          for (int j = 0; j < 8; ++j){
            const int k = ks*16 + lh*8 + j;
            raw[j] = (k < 10) ? (short)f2bf(W1[col*10 + k]) : (short)0;
          }
          b[nt] = __builtin_bit_cast(bf16x8, raw);
        }
      }
#pragma unroll
      for (int nt = 0; nt < 4; ++nt){
        c[0][nt] = mfma32(a0, b[nt], c[0][nt]);
        c[1][nt] = mfma32(a1, b[nt], c[1][nt]);
      }
    }
#pragma unroll
    for (int nt = 0; nt < 4; ++nt){
      const int col = wid*128 + nt*32 + l31;
      const float bv = b1[col];
#pragma unroll
      for (int mt = 0; mt < 2; ++mt)
#pragma unroll
        for (int r = 0; r < 16; ++r){
          const int row = mt*32 + (r & 3) + 8*(r >> 2) + 4*lh;
          *reinterpret_cast<unsigned short*>(h1 + row*H1S + col*2) =
              f2bf(fmaxf(c[mt][nt][r] + bv, 0.f));
        }
    }
  }
  __syncthreads();

  // ---- 4. GEMM2: per wave 64 rows x 128 cols, K=1024
  //        ring-3 / distance-2 software pipeline. B stride per ks = 1024 BYTES
  //        (64 lanes x 8 shorts), A stride per ks = 32 BYTES (16 bf16).
  f32x16 acc[2][4];
#pragma unroll
  for (int mt = 0; mt < 2; ++mt)
#pragma unroll
    for (int nt = 0; nt < 4; ++nt) acc[mt][nt] = zero16();

  if constexpr (BFWS){
    const char* pB0 = (const char*)(w2opt + ((size_t)(wid*4 + 0)*4096 + l) * 8);
    const char* pB1 = (const char*)(w2opt + ((size_t)(wid*4 + 1)*4096 + l) * 8);
    const char* pB2 = (const char*)(w2opt + ((size_t)(wid*4 + 2)*4096 + l) * 8);
    const char* pB3 = (const char*)(w2opt + ((size_t)(wid*4 + 3)*4096 + l) * 8);
    int ao = l31*H1S + lh*16;                 // A base byte offset into h1

    bf16x8 Bst[3][4];
    bf16x8 Ast[3][2];

#define LDB(S, OFF) do{                                    \
      Bst[S][0] = ld16(pB0 + (OFF));                       \
      Bst[S][1] = ld16(pB1 + (OFF));                       \
      Bst[S][2] = ld16(pB2 + (OFF));                       \
      Bst[S][3] = ld16(pB3 + (OFF));                       \
    }while(0)
#define LDA(S, OFF) do{                                    \
      Ast[S][0] = ld16(h1 + ao + (OFF));                   \
      Ast[S][1] = ld16(h1 + ao + 32*H1S + (OFF));          \
    }while(0)
#define MM8(S) do{                                         \
      __builtin_amdgcn_s_setprio(1);                       \
      acc[0][0] = mfma32(Ast[S][0], Bst[S][0], acc[0][0]); \
      acc[1][0] = mfma32(Ast[S][1], Bst[S][0], acc[1][0]); \
      acc[0][1] = mfma32(Ast[S][0], Bst[S][1], acc[0][1]); \
      acc[1][1] = mfma32(Ast[S][1], Bst[S][1], acc[1][1]); \
      acc[0][2] = mfma32(Ast[S][0], Bst[S][2], acc[0][2]); \
      acc[1][2] = mfma32(Ast[S][1], Bst[S][2], acc[1][2]); \
      acc[0][3] = mfma32(Ast[S][0], Bst[S][3], acc[0][3]); \
      acc[1][3] = mfma32(Ast[S][1], Bst[S][3], acc[1][3]); \
      __builtin_amdgcn_s_setprio(0);                       \
    }while(0)

    // prologue: ks=0 -> set0, ks=1 -> set1   (B: 1024 B per ks; A: 32 B per ks)
    LDB(0, 0);     LDA(0, 0);
    LDB(1, 1024);  LDA(1, 32);

    for (int t = 0; t < 21; ++t){            // ks = 3t, 3t+1, 3t+2  (0..62)
      LDB(2, 2048); LDA(2, 64);              // prefetch ks=3t+2 -> set2
      MM8(0);                                // compute ks=3t
      LDB(0, 3072); LDA(0, 96);              // prefetch ks=3t+3 -> set0
      MM8(1);                                // compute ks=3t+1
      if (t < 20){ LDB(1, 4096); LDA(1, 128); }  // prefetch ks=3t+4 -> set1
      MM8(2);                                // compute ks=3t+2
      pB0 += 3072; pB1 += 3072; pB2 += 3072; pB3 += 3072; ao += 96;
    }
    MM8(0);                                  // ks = 63 (staged at t=20, set0)
#undef LDB
#undef LDA
#undef MM8
  } else {
    // fallback (no workspace): simple loop with in-flight f32->bf16 conversion
    const int aA0 = l31*H1S + lh*16;
    for (int ks = 0; ks < 64; ++ks){
      bf16x8 A0 = ld16(h1 + aA0 + ks*32);
      bf16x8 A1 = ld16(h1 + aA0 + 32*H1S + ks*32);
      bf16x8 B[4];
#pragma unroll
      for (int nt = 0; nt < 4; ++nt){
        const int col = wid*128 + nt*32 + l31;
        const float* p = W2f + (size_t)col*NEUR + ks*16 + lh*8;
        s16x8 raw;
#pragma unroll
        for (int j = 0; j < 8; ++j) raw[j] = (short)f2bf(p[j]);
        B[nt] = __builtin_bit_cast(bf16x8, raw);
      }
#pragma unroll
      for (int nt = 0; nt < 4; ++nt){
        acc[0][nt] = mfma32(A0, B[nt], acc[0][nt]);
        acc[1][nt] = mfma32(A1, B[nt], acc[1][nt]);
      }
    }
  }
  __syncthreads();   // everyone done reading h1

  // ---- 5. h2 = relu(acc + b2) -> back into h1 (bf16, padded layout)
#pragma unroll
  for (int nt = 0; nt < 4; ++nt){
    const int col = wid*128 + nt*32 + l31;
    const float bv = b2[col];
#pragma unroll
    for (int mt = 0; mt < 2; ++mt)
#pragma unroll
      for (int r = 0; r < 16; ++r){
        const int row = mt*32 + (r & 3) + 8*(r >> 2) + 4*lh;
        *reinterpret_cast<unsigned short*>(h1 + row*H1S + col*2) =
            f2bf(fmaxf(acc[mt][nt][r] + bv, 0.f));
      }
  }
  __syncthreads();

  // ---- 6. GEMM3 (f32 VALU): wave wid owns rows wid*8 .. wid*8+7
  float s[8][3];
#pragma unroll
  for (int rr = 0; rr < 8; ++rr)
#pragma unroll
    for (int j = 0; j < 3; ++j) s[rr][j] = 0.f;

#pragma unroll
  for (int h = 0; h < 2; ++h){
    const int k0 = h*512 + l*8;
    float w3v[3][8];
#pragma unroll
    for (int j = 0; j < 3; ++j)
#pragma unroll
      for (int i = 0; i < 8; ++i) w3v[j][i] = W3[j*NEUR + k0 + i];
#pragma unroll
    for (int rr = 0; rr < 8; ++rr){
      const int row = wid*8 + rr;
      s16x8 raw = *reinterpret_cast<const s16x8*>(h1 + row*H1S + k0*2);
#pragma unroll
      for (int i = 0; i < 8; ++i){
        const float hv = bf2f((unsigned short)raw[i]);
        s[rr][0] += hv * w3v[0][i];
        s[rr][1] += hv * w3v[1][i];
        s[rr][2] += hv * w3v[2][i];
      }
    }
  }
#pragma unroll
  for (int off = 1; off < 64; off <<= 1)
#pragma unroll
    for (int rr = 0; rr < 8; ++rr)
#pragma unroll
      for (int j = 0; j < 3; ++j) s[rr][j] += __shfl_xor(s[rr][j], off, 64);

  if (l == 0){
#pragma unroll
    for (int rr = 0; rr < 8; ++rr){
      const int row = wid*8 + rr;
#pragma unroll
      for (int j = 0; j < 3; ++j)
        out[(rbase + row)*3 + j] = 1.f / (1.f + __expf(-(s[rr][j] + b3[j])));
    }
  }
}

extern "C" void kernel_launch(void* const* d_in, const int* in_sizes, int n_in,
                              void* d_out, int out_size, void* d_ws, size_t ws_size,
                              hipStream_t stream){
  const float* x  = (const float*)d_in[0];
  const float* Wx = (const float*)d_in[1];
  const float* bx = (const float*)d_in[2];
  const float* Wu = (const float*)d_in[3];
  const float* bu = (const float*)d_in[4];
  const float* W1 = (const float*)d_in[5];
  const float* b1 = (const float*)d_in[6];
  const float* W2 = (const float*)d_in[7];
  const float* b2 = (const float*)d_in[8];
  const float* W3 = (const float*)d_in[9];
  const float* b3 = (const float*)d_in[10];
  float* out = (float*)d_out;

  const int batch   = in_sizes[0] / 25;
  const int nblocks = batch / BM;
  const size_t ws_need = (size_t)(32*64*64*8 + 4096*8) * sizeof(unsigned short); // ~2.1 MB
  const int smem = 5120 + BM*H1S;   // 137216 B

  if (ws_size >= ws_need){
    unsigned short* w2opt = (unsigned short*)d_ws;
    unsigned short* w1opt = w2opt + (size_t)32*64*64*8;
    prep_kernel<<<512, 256, 0, stream>>>(W1, W2, w2opt, w1opt);
    hipFuncSetAttribute(reinterpret_cast<const void*>(mlp_kernel<true>),
                        hipFuncAttributeMaxDynamicSharedMemorySize, smem);
    mlp_kernel<true><<<nblocks, THREADS, smem, stream>>>(
        x, Wx, bx, Wu, bu, W1, b1, W2, b2, W3, b3, w2opt, w1opt, out);
  } else {
    hipFuncSetAttribute(reinterpret_cast<const void*>(mlp_kernel<false>),
                        hipFuncAttributeMaxDynamicSharedMemorySize, smem);
    mlp_kernel<false><<<nblocks, THREADS, smem, stream>>>(
        x, Wx, bx, Wu, bu, W1, b1, W2, b2, W3, b3, nullptr, nullptr, out);
  }
}

// Round 7
// 323.840 us; speedup vs baseline: 1.1642x; 1.1642x over previous
//
#include <hip/hip_runtime.h>
#include <stdint.h>

#define NEUR 1024
#define BM 64
#define THREADS 512
#define H1S 2064   // h1 row stride in bytes (1024*2 + 16 pad -> bank spread, imm-foldable)

typedef short  s16x8  __attribute__((ext_vector_type(8)));
typedef __bf16 bf16x8 __attribute__((ext_vector_type(8)));
typedef float  f32x16 __attribute__((ext_vector_type(16)));

__device__ __forceinline__ unsigned short f2bf(float f){
  unsigned u = __builtin_bit_cast(unsigned, f);
  u += 0x7FFFu + ((u >> 16) & 1u);          // round-to-nearest-even
  return (unsigned short)(u >> 16);
}
__device__ __forceinline__ float bf2f(unsigned short h){
  unsigned u = ((unsigned)h) << 16;
  return __builtin_bit_cast(float, u);
}
__device__ __forceinline__ f32x16 mfma32(bf16x8 a, bf16x8 b, f32x16 c){
  return __builtin_amdgcn_mfma_f32_32x32x16_bf16(a, b, c, 0, 0, 0);
}
__device__ __forceinline__ f32x16 zero16(){
  f32x16 v;
#pragma unroll
  for (int r = 0; r < 16; ++r) v[r] = 0.f;
  return v;
}
__device__ __forceinline__ bf16x8 ld16(const void* p){
  return __builtin_bit_cast(bf16x8, *reinterpret_cast<const s16x8*>(p));
}

// Pre-swizzle weights into MFMA-fragment order so GEMM loads are coalesced.
// w2opt[((nt*64 + ks)*64 + l)*8 + j] = bf16(W2[nt*32 + (l&31)][ks*16 + (l>>5)*8 + j])
// w1opt[((nt*2  + ks)*64 + l)*8 + j] = bf16(W1 padded to K=32, same fragment map)
__global__ void prep_kernel(const float* __restrict__ W1, const float* __restrict__ W2,
                            unsigned short* __restrict__ w2opt, unsigned short* __restrict__ w1opt){
  const int nchunks = NEUR * 128;            // 8-float chunks of W2 (read-coalesced)
  const int total = nchunks + 4096;          // + w1opt lane-blocks
  for (int i = blockIdx.x*blockDim.x + threadIdx.x; i < total; i += gridDim.x*blockDim.x){
    if (i < nchunks){
      const int col = i >> 7, c8 = i & 127;
      const float* src = W2 + (size_t)col*NEUR + c8*8;
      const int ks = c8 >> 1, lf = c8 & 1, lane = lf*32 + (col & 31), nt = col >> 5;
      unsigned short* dst = w2opt + (((size_t)(nt*64 + ks)*64 + lane) * 8);
#pragma unroll
      for (int j = 0; j < 8; ++j) dst[j] = f2bf(src[j]);
    } else {
      const int o = i - nchunks;             // ((nt*2+ks)*64 + lane)
      const int nt = o >> 7, ks = (o >> 6) & 1, lane = o & 63;
      const int col = nt*32 + (lane & 31);
      unsigned short* dst = w1opt + (size_t)o * 8;
#pragma unroll
      for (int j = 0; j < 8; ++j){
        const int k = ks*16 + (lane >> 5)*8 + j;
        dst[j] = (k < 10) ? f2bf(W1[col*10 + k]) : (unsigned short)0;
      }
    }
  }
}

template<bool BFWS>
__global__ __launch_bounds__(THREADS, 2) void mlp_kernel(
    const float* __restrict__ x,
    const float* __restrict__ Wx, const float* __restrict__ bxp,
    const float* __restrict__ Wu, const float* __restrict__ bup,
    const float* __restrict__ W1, const float* __restrict__ b1,
    const float* __restrict__ W2f, const float* __restrict__ b2,
    const float* __restrict__ W3, const float* __restrict__ b3,
    const unsigned short* __restrict__ w2opt, const unsigned short* __restrict__ w1opt,
    float* __restrict__ out)
{
  extern __shared__ char smem[];
  unsigned short* l1p = (unsigned short*)smem;   // [64][40] bf16 (5120 B, padded stride)
  char* h1            = smem + 5120;             // 64 rows x 2064 B (padded), bf16

  const int tid = threadIdx.x;
  const int l   = tid & 63;
  const int wid = tid >> 6;                      // 8 waves
  const int l31 = l & 31;
  const int lh  = l >> 5;
  const long rbase = (long)blockIdx.x * BM;

  // ---- 1. stage x tile (64*25 f32), overlaying h1 region
  float* xs = (float*)h1;
  for (int i = tid; i < BM*25; i += THREADS) xs[i] = x[rbase*25 + i];
  __syncthreads();

  // ---- 2. l1 features (f32 exact), bf16-pad to K=32 in l1p
  if (tid < BM){
    const float* xr = xs + tid*25;
    float l1v[10];
#pragma unroll
    for (int g = 0; g < 3; ++g)
#pragma unroll
      for (int o = 0; o < 2; ++o){
        float s = bxp[o];
#pragma unroll
        for (int i = 0; i < 5; ++i) s += xr[g + 3*i] * Wx[o*5 + i];
        l1v[g*2 + o] = fmaxf(s, 0.f);
      }
#pragma unroll
    for (int g = 0; g < 2; ++g)
#pragma unroll
      for (int o = 0; o < 2; ++o){
        float s = bup[o];
#pragma unroll
        for (int i = 0; i < 5; ++i) s += xr[15 + g + 2*i] * Wu[o*5 + i];
        l1v[6 + g*2 + o] = fmaxf(s, 0.f);
      }
    unsigned short* dst = l1p + tid*40;
#pragma unroll
    for (int i = 0; i < 10; ++i) dst[i] = f2bf(l1v[i]);
#pragma unroll
    for (int i = 10; i < 32; ++i) dst[i] = 0;
  }
  __syncthreads();

  // ---- 3. GEMM1: h1[64][wid*128 .. +128) = relu(l1 @ W1^T + b1)
  {
    f32x16 c[2][4];
#pragma unroll
    for (int mt = 0; mt < 2; ++mt)
#pragma unroll
      for (int nt = 0; nt < 4; ++nt) c[mt][nt] = zero16();

#pragma unroll
    for (int ks = 0; ks < 2; ++ks){
      bf16x8 a0 = ld16(smem + l31*80 + ks*32 + lh*16);
      bf16x8 a1 = ld16(smem + (32 + l31)*80 + ks*32 + lh*16);
      bf16x8 b[4];
#pragma unroll
      for (int nt = 0; nt < 4; ++nt){
        if constexpr (BFWS){
          b[nt] = ld16(w1opt + (((size_t)((wid*4 + nt)*2 + ks)*64 + l) * 8));
        } else {
          const int col = wid*128 + nt*32 + l31;
          s16x8 raw;
#pragma unroll
          for (int j = 0; j < 8; ++j){
            const int k = ks*16 + lh*8 + j;
            raw[j] = (k < 10) ? (short)f2bf(W1[col*10 + k]) : (short)0;
          }
          b[nt] = __builtin_bit_cast(bf16x8, raw);
        }
      }
#pragma unroll
      for (int nt = 0; nt < 4; ++nt){
        c[0][nt] = mfma32(a0, b[nt], c[0][nt]);
        c[1][nt] = mfma32(a1, b[nt], c[1][nt]);
      }
    }
#pragma unroll
    for (int nt = 0; nt < 4; ++nt){
      const int col = wid*128 + nt*32 + l31;
      const float bv = b1[col];
#pragma unroll
      for (int mt = 0; mt < 2; ++mt)
#pragma unroll
        for (int r = 0; r < 16; ++r){
          const int row = mt*32 + (r & 3) + 8*(r >> 2) + 4*lh;
          *reinterpret_cast<unsigned short*>(h1 + row*H1S + col*2) =
              f2bf(fmaxf(c[mt][nt][r] + bv, 0.f));
        }
    }
  }
  __syncthreads();

  // ---- 4. GEMM2: per wave 64 rows x 128 cols, K=1024
  //        depth-1 ping-pong, BRANCH-FREE steady-state body (peeled epilogue),
  //        wave-staggered K start (wid*8) so co-resident waves' load/MFMA
  //        phases interleave instead of lockstepping.
  f32x16 acc[2][4];
#pragma unroll
  for (int mt = 0; mt < 2; ++mt)
#pragma unroll
    for (int nt = 0; nt < 4; ++nt) acc[mt][nt] = zero16();

  if constexpr (BFWS){
    const char* const wB0 = (const char*)(w2opt + ((size_t)(wid*4 + 0)*4096 + l) * 8);
    const char* const wB1 = (const char*)(w2opt + ((size_t)(wid*4 + 1)*4096 + l) * 8);
    const char* const wB2 = (const char*)(w2opt + ((size_t)(wid*4 + 2)*4096 + l) * 8);
    const char* const wB3 = (const char*)(w2opt + ((size_t)(wid*4 + 3)*4096 + l) * 8);
    const int aBase = l31*H1S + lh*16;

    bf16x8 Aa0, Aa1, Ab0, Ab1;
    bf16x8 Ba0, Ba1, Ba2, Ba3, Bb0, Bb1, Bb2, Bb3;

#define LDB_A(OFF) do{ Ba0 = ld16(pb0 + (OFF)); Ba1 = ld16(pb1 + (OFF));  \
                       Ba2 = ld16(pb2 + (OFF)); Ba3 = ld16(pb3 + (OFF)); }while(0)
#define LDB_B(OFF) do{ Bb0 = ld16(pb0 + (OFF)); Bb1 = ld16(pb1 + (OFF));  \
                       Bb2 = ld16(pb2 + (OFF)); Bb3 = ld16(pb3 + (OFF)); }while(0)
#define LDA_A(OFF) do{ Aa0 = ld16(h1 + ao + (OFF)); Aa1 = ld16(h1 + ao + 32*H1S + (OFF)); }while(0)
#define LDA_B(OFF) do{ Ab0 = ld16(h1 + ao + (OFF)); Ab1 = ld16(h1 + ao + 32*H1S + (OFF)); }while(0)
#define MM8_A do{ __builtin_amdgcn_s_setprio(1);            \
      acc[0][0] = mfma32(Aa0, Ba0, acc[0][0]);              \
      acc[1][0] = mfma32(Aa1, Ba0, acc[1][0]);              \
      acc[0][1] = mfma32(Aa0, Ba1, acc[0][1]);              \
      acc[1][1] = mfma32(Aa1, Ba1, acc[1][1]);              \
      acc[0][2] = mfma32(Aa0, Ba2, acc[0][2]);              \
      acc[1][2] = mfma32(Aa1, Ba2, acc[1][2]);              \
      acc[0][3] = mfma32(Aa0, Ba3, acc[0][3]);              \
      acc[1][3] = mfma32(Aa1, Ba3, acc[1][3]);              \
      __builtin_amdgcn_s_setprio(0); }while(0)
#define MM8_B do{ __builtin_amdgcn_s_setprio(1);            \
      acc[0][0] = mfma32(Ab0, Bb0, acc[0][0]);              \
      acc[1][0] = mfma32(Ab1, Bb0, acc[1][0]);              \
      acc[0][1] = mfma32(Ab0, Bb1, acc[0][1]);              \
      acc[1][1] = mfma32(Ab1, Bb1, acc[1][1]);              \
      acc[0][2] = mfma32(Ab0, Bb2, acc[0][2]);              \
      acc[1][2] = mfma32(Ab1, Bb2, acc[1][2]);              \
      acc[0][3] = mfma32(Ab0, Bb3, acc[0][3]);              \
      acc[1][3] = mfma32(Ab1, Bb3, acc[1][3]);              \
      __builtin_amdgcn_s_setprio(0); }while(0)

    // run n K-steps starting at ks0 (n even >= 2); B stride/ks = 1024 B, A = 32 B
    auto run_seg = [&](int ks0, int n){
      const char* pb0 = wB0 + (size_t)ks0*1024;
      const char* pb1 = wB1 + (size_t)ks0*1024;
      const char* pb2 = wB2 + (size_t)ks0*1024;
      const char* pb3 = wB3 + (size_t)ks0*1024;
      int ao = aBase + ks0*32;
      LDB_A(0); LDA_A(0);
      for (int t = 0; t + 2 < n; t += 2){      // branch-free body
        LDB_B(1024); LDA_B(32);
        MM8_A;
        LDB_A(2048); LDA_A(64);
        MM8_B;
        pb0 += 2048; pb1 += 2048; pb2 += 2048; pb3 += 2048; ao += 64;
      }
      LDB_B(1024); LDA_B(32);                  // peeled final pair
      MM8_A;
      MM8_B;
    };

    const int koff = wid * 8;                  // stagger: 8 distinct phase offsets
    run_seg(koff, 64 - koff);
    if (koff) run_seg(0, koff);
#undef LDB_A
#undef LDB_B
#undef LDA_A
#undef LDA_B
#undef MM8_A
#undef MM8_B
  } else {
    // fallback (no workspace): simple loop with in-flight f32->bf16 conversion
    const int aA0 = l31*H1S + lh*16;
    for (int ks = 0; ks < 64; ++ks){
      bf16x8 A0 = ld16(h1 + aA0 + ks*32);
      bf16x8 A1 = ld16(h1 + aA0 + 32*H1S + ks*32);
      bf16x8 B[4];
#pragma unroll
      for (int nt = 0; nt < 4; ++nt){
        const int col = wid*128 + nt*32 + l31;
        const float* p = W2f + (size_t)col*NEUR + ks*16 + lh*8;
        s16x8 raw;
#pragma unroll
        for (int j = 0; j < 8; ++j) raw[j] = (short)f2bf(p[j]);
        B[nt] = __builtin_bit_cast(bf16x8, raw);
      }
#pragma unroll
      for (int nt = 0; nt < 4; ++nt){
        acc[0][nt] = mfma32(A0, B[nt], acc[0][nt]);
        acc[1][nt] = mfma32(A1, B[nt], acc[1][nt]);
      }
    }
  }
  __syncthreads();   // everyone done reading h1

  // ---- 5. h2 = relu(acc + b2) -> back into h1 (bf16, padded layout)
#pragma unroll
  for (int nt = 0; nt < 4; ++nt){
    const int col = wid*128 + nt*32 + l31;
    const float bv = b2[col];
#pragma unroll
    for (int mt = 0; mt < 2; ++mt)
#pragma unroll
      for (int r = 0; r < 16; ++r){
        const int row = mt*32 + (r & 3) + 8*(r >> 2) + 4*lh;
        *reinterpret_cast<unsigned short*>(h1 + row*H1S + col*2) =
            f2bf(fmaxf(acc[mt][nt][r] + bv, 0.f));
      }
  }
  __syncthreads();

  // ---- 6. GEMM3 (f32 VALU): wave wid owns rows wid*8 .. wid*8+7
  float s[8][3];
#pragma unroll
  for (int rr = 0; rr < 8; ++rr)
#pragma unroll
    for (int j = 0; j < 3; ++j) s[rr][j] = 0.f;

#pragma unroll
  for (int h = 0; h < 2; ++h){
    const int k0 = h*512 + l*8;
    float w3v[3][8];
#pragma unroll
    for (int j = 0; j < 3; ++j)
#pragma unroll
      for (int i = 0; i < 8; ++i) w3v[j][i] = W3[j*NEUR + k0 + i];
#pragma unroll
    for (int rr = 0; rr < 8; ++rr){
      const int row = wid*8 + rr;
      s16x8 raw = *reinterpret_cast<const s16x8*>(h1 + row*H1S + k0*2);
#pragma unroll
      for (int i = 0; i < 8; ++i){
        const float hv = bf2f((unsigned short)raw[i]);
        s[rr][0] += hv * w3v[0][i];
        s[rr][1] += hv * w3v[1][i];
        s[rr][2] += hv * w3v[2][i];
      }
    }
  }
#pragma unroll
  for (int off = 1; off < 64; off <<= 1)
#pragma unroll
    for (int rr = 0; rr < 8; ++rr)
#pragma unroll
      for (int j = 0; j < 3; ++j) s[rr][j] += __shfl_xor(s[rr][j], off, 64);

  if (l == 0){
#pragma unroll
    for (int rr = 0; rr < 8; ++rr){
      const int row = wid*8 + rr;
#pragma unroll
      for (int j = 0; j < 3; ++j)
        out[(rbase + row)*3 + j] = 1.f / (1.f + __expf(-(s[rr][j] + b3[j])));
    }
  }
}

extern "C" void kernel_launch(void* const* d_in, const int* in_sizes, int n_in,
                              void* d_out, int out_size, void* d_ws, size_t ws_size,
                              hipStream_t stream){
  const float* x  = (const float*)d_in[0];
  const float* Wx = (const float*)d_in[1];
  const float* bx = (const float*)d_in[2];
  const float* Wu = (const float*)d_in[3];
  const float* bu = (const float*)d_in[4];
  const float* W1 = (const float*)d_in[5];
  const float* b1 = (const float*)d_in[6];
  const float* W2 = (const float*)d_in[7];
  const float* b2 = (const float*)d_in[8];
  const float* W3 = (const float*)d_in[9];
  const float* b3 = (const float*)d_in[10];
  float* out = (float*)d_out;

  const int batch   = in_sizes[0] / 25;
  const int nblocks = batch / BM;
  const size_t ws_need = (size_t)(32*64*64*8 + 4096*8) * sizeof(unsigned short); // ~2.1 MB
  const int smem = 5120 + BM*H1S;   // 137216 B

  if (ws_size >= ws_need){
    unsigned short* w2opt = (unsigned short*)d_ws;
    unsigned short* w1opt = w2opt + (size_t)32*64*64*8;
    prep_kernel<<<512, 256, 0, stream>>>(W1, W2, w2opt, w1opt);
    hipFuncSetAttribute(reinterpret_cast<const void*>(mlp_kernel<true>),
                        hipFuncAttributeMaxDynamicSharedMemorySize, smem);
    mlp_kernel<true><<<nblocks, THREADS, smem, stream>>>(
        x, Wx, bx, Wu, bu, W1, b1, W2, b2, W3, b3, w2opt, w1opt, out);
  } else {
    hipFuncSetAttribute(reinterpret_cast<const void*>(mlp_kernel<false>),
                        hipFuncAttributeMaxDynamicSharedMemorySize, smem);
    mlp_kernel<false><<<nblocks, THREADS, smem, stream>>>(
        x, Wx, bx, Wu, bu, W1, b1, W2, b2, W3, b3, nullptr, nullptr, out);
  }
}

// Round 8
// 309.836 us; speedup vs baseline: 1.2168x; 1.0452x over previous
//
#include <hip/hip_runtime.h>
#include <stdint.h>

#define NEUR 1024
#define BM 64
#define THREADS 512
#define H1S 2064   // h1 row stride in bytes (1024*2 + 16 pad -> 4-way max on A reads)

typedef short  s16x8  __attribute__((ext_vector_type(8)));
typedef __bf16 bf16x8 __attribute__((ext_vector_type(8)));
typedef float  f32x16 __attribute__((ext_vector_type(16)));

__device__ __forceinline__ unsigned short f2bf(float f){
  unsigned u = __builtin_bit_cast(unsigned, f);
  u += 0x7FFFu + ((u >> 16) & 1u);          // round-to-nearest-even
  return (unsigned short)(u >> 16);
}
__device__ __forceinline__ float bf2f(unsigned short h){
  unsigned u = ((unsigned)h) << 16;
  return __builtin_bit_cast(float, u);
}
__device__ __forceinline__ f32x16 mfma32(bf16x8 a, bf16x8 b, f32x16 c){
  return __builtin_amdgcn_mfma_f32_32x32x16_bf16(a, b, c, 0, 0, 0);
}
__device__ __forceinline__ f32x16 zero16(){
  f32x16 v;
#pragma unroll
  for (int r = 0; r < 16; ++r) v[r] = 0.f;
  return v;
}
__device__ __forceinline__ bf16x8 ld16(const void* p){
  return __builtin_bit_cast(bf16x8, *reinterpret_cast<const s16x8*>(p));
}

// Pre-swizzle weights into MFMA-fragment order so GEMM loads are coalesced.
// w2opt[((nt*64 + ks)*64 + l)*8 + j] = bf16(W2[nt*32 + (l&31)][ks*16 + (l>>5)*8 + j])
// w1opt[((nt*2  + ks)*64 + l)*8 + j] = bf16(W1 padded to K=32, same fragment map)
__global__ void prep_kernel(const float* __restrict__ W1, const float* __restrict__ W2,
                            unsigned short* __restrict__ w2opt, unsigned short* __restrict__ w1opt){
  const int nchunks = NEUR * 128;            // 8-float chunks of W2 (read-coalesced)
  const int total = nchunks + 4096;          // + w1opt lane-blocks
  for (int i = blockIdx.x*blockDim.x + threadIdx.x; i < total; i += gridDim.x*blockDim.x){
    if (i < nchunks){
      const int col = i >> 7, c8 = i & 127;
      const float* src = W2 + (size_t)col*NEUR + c8*8;
      const int ks = c8 >> 1, lf = c8 & 1, lane = lf*32 + (col & 31), nt = col >> 5;
      unsigned short* dst = w2opt + (((size_t)(nt*64 + ks)*64 + lane) * 8);
#pragma unroll
      for (int j = 0; j < 8; ++j) dst[j] = f2bf(src[j]);
    } else {
      const int o = i - nchunks;             // ((nt*2+ks)*64 + lane)
      const int nt = o >> 7, ks = (o >> 6) & 1, lane = o & 63;
      const int col = nt*32 + (lane & 31);
      unsigned short* dst = w1opt + (size_t)o * 8;
#pragma unroll
      for (int j = 0; j < 8; ++j){
        const int k = ks*16 + (lane >> 5)*8 + j;
        dst[j] = (k < 10) ? f2bf(W1[col*10 + k]) : (unsigned short)0;
      }
    }
  }
}

template<bool BFWS>
__global__ __launch_bounds__(THREADS, 2) void mlp_kernel(
    const float* __restrict__ x,
    const float* __restrict__ Wx, const float* __restrict__ bxp,
    const float* __restrict__ Wu, const float* __restrict__ bup,
    const float* __restrict__ W1, const float* __restrict__ b1,
    const float* __restrict__ W2f, const float* __restrict__ b2,
    const float* __restrict__ W3, const float* __restrict__ b3,
    const unsigned short* __restrict__ w2opt, const unsigned short* __restrict__ w1opt,
    float* __restrict__ out)
{
  extern __shared__ char smem[];
  unsigned short* l1p = (unsigned short*)smem;   // [64][40] bf16 (5120 B, padded stride)
  char* h1            = smem + 5120;             // 64 rows x 2064 B (padded), bf16

  const int tid = threadIdx.x;
  const int l   = tid & 63;
  const int wid = tid >> 6;                      // 8 waves
  const int l31 = l & 31;
  const int lh  = l >> 5;
  const long rbase = (long)blockIdx.x * BM;

  // ---- 1. stage x tile (64*25 f32), overlaying h1 region
  float* xs = (float*)h1;
  for (int i = tid; i < BM*25; i += THREADS) xs[i] = x[rbase*25 + i];
  __syncthreads();

  // ---- 2. l1 features (f32 exact), bf16-pad to K=32 in l1p
  if (tid < BM){
    const float* xr = xs + tid*25;
    float l1v[10];
#pragma unroll
    for (int g = 0; g < 3; ++g)
#pragma unroll
      for (int o = 0; o < 2; ++o){
        float s = bxp[o];
#pragma unroll
        for (int i = 0; i < 5; ++i) s += xr[g + 3*i] * Wx[o*5 + i];
        l1v[g*2 + o] = fmaxf(s, 0.f);
      }
#pragma unroll
    for (int g = 0; g < 2; ++g)
#pragma unroll
      for (int o = 0; o < 2; ++o){
        float s = bup[o];
#pragma unroll
        for (int i = 0; i < 5; ++i) s += xr[15 + g + 2*i] * Wu[o*5 + i];
        l1v[6 + g*2 + o] = fmaxf(s, 0.f);
      }
    unsigned short* dst = l1p + tid*40;
#pragma unroll
    for (int i = 0; i < 10; ++i) dst[i] = f2bf(l1v[i]);
#pragma unroll
    for (int i = 10; i < 32; ++i) dst[i] = 0;
  }
  __syncthreads();

  // ---- 3. GEMM1: h1[64][wid*128 .. +128) = relu(l1 @ W1^T + b1)
  {
    f32x16 c[2][4];
#pragma unroll
    for (int mt = 0; mt < 2; ++mt)
#pragma unroll
      for (int nt = 0; nt < 4; ++nt) c[mt][nt] = zero16();

#pragma unroll
    for (int ks = 0; ks < 2; ++ks){
      bf16x8 a0 = ld16(smem + l31*80 + ks*32 + lh*16);
      bf16x8 a1 = ld16(smem + (32 + l31)*80 + ks*32 + lh*16);
      bf16x8 b[4];
#pragma unroll
      for (int nt = 0; nt < 4; ++nt){
        if constexpr (BFWS){
          b[nt] = ld16(w1opt + (((size_t)((wid*4 + nt)*2 + ks)*64 + l) * 8));
        } else {
          const int col = wid*128 + nt*32 + l31;
          s16x8 raw;
#pragma unroll
          for (int j = 0; j < 8; ++j){
            const int k = ks*16 + lh*8 + j;
            raw[j] = (k < 10) ? (short)f2bf(W1[col*10 + k]) : (short)0;
          }
          b[nt] = __builtin_bit_cast(bf16x8, raw);
        }
      }
#pragma unroll
      for (int nt = 0; nt < 4; ++nt){
        c[0][nt] = mfma32(a0, b[nt], c[0][nt]);
        c[1][nt] = mfma32(a1, b[nt], c[1][nt]);
      }
    }
#pragma unroll
    for (int nt = 0; nt < 4; ++nt){
      const int col = wid*128 + nt*32 + l31;
      const float bv = b1[col];
#pragma unroll
      for (int mt = 0; mt < 2; ++mt)
#pragma unroll
        for (int r = 0; r < 16; ++r){
          const int row = mt*32 + (r & 3) + 8*(r >> 2) + 4*lh;
          *reinterpret_cast<unsigned short*>(h1 + row*H1S + col*2) =
              f2bf(fmaxf(c[mt][nt][r] + bv, 0.f));
        }
    }
  }
  __syncthreads();

  // ---- 4. GEMM2: per wave 64 rows x 128 cols, K=1024.
  //   MM4-granular software pipeline: same 96 staging VGPRs as a depth-1 MM8
  //   ping-pong, but every load issued 3 MM4s (~384 SIMD-cyc) ahead of its
  //   consumer. Branch-free 31-iter body. B stride/ks = 1024 B, A = 32 B.
  f32x16 acc[2][4];
#pragma unroll
  for (int mt = 0; mt < 2; ++mt)
#pragma unroll
    for (int nt = 0; nt < 4; ++nt) acc[mt][nt] = zero16();

  if constexpr (BFWS){
    const char* pb0 = (const char*)(w2opt + ((size_t)(wid*4 + 0)*4096 + l) * 8);
    const char* pb1 = (const char*)(w2opt + ((size_t)(wid*4 + 1)*4096 + l) * 8);
    const char* pb2 = (const char*)(w2opt + ((size_t)(wid*4 + 2)*4096 + l) * 8);
    const char* pb3 = (const char*)(w2opt + ((size_t)(wid*4 + 3)*4096 + l) * 8);
    int ao = l31*H1S + lh*16;

    bf16x8 Aa0, Aa1, Ab0, Ab1;
    bf16x8 P0a, P0b;   // B tiles{0,1}, even-k buffer
    bf16x8 Q0a, Q0b;   // B tiles{2,3}, even-k buffer
    bf16x8 P1a, P1b;   // B tiles{0,1}, odd-k buffer
    bf16x8 Q1a, Q1b;   // B tiles{2,3}, odd-k buffer

#define MM4_01(A0_,A1_,B0_,B1_) do{ __builtin_amdgcn_s_setprio(1);            \
      acc[0][0]=mfma32(A0_,B0_,acc[0][0]); acc[1][0]=mfma32(A1_,B0_,acc[1][0]);\
      acc[0][1]=mfma32(A0_,B1_,acc[0][1]); acc[1][1]=mfma32(A1_,B1_,acc[1][1]);\
      __builtin_amdgcn_s_setprio(0); }while(0)
#define MM4_23(A0_,A1_,B0_,B1_) do{ __builtin_amdgcn_s_setprio(1);            \
      acc[0][2]=mfma32(A0_,B0_,acc[0][2]); acc[1][2]=mfma32(A1_,B0_,acc[1][2]);\
      acc[0][3]=mfma32(A0_,B1_,acc[0][3]); acc[1][3]=mfma32(A1_,B1_,acc[1][3]);\
      __builtin_amdgcn_s_setprio(0); }while(0)

    // prologue: k0 tiles01 -> P0, k0 tiles23 -> Q0, k1 tiles01 -> P1, A(k0)
    P0a = ld16(pb0);          P0b = ld16(pb1);
    Q0a = ld16(pb2);          Q0b = ld16(pb3);
    P1a = ld16(pb0 + 1024);   P1b = ld16(pb1 + 1024);
    Aa0 = ld16(h1 + ao);      Aa1 = ld16(h1 + ao + 32*H1S);

    for (int t = 0; t < 31; ++t){
      // k0 = 2t; pointers sit at k0
      Q1a = ld16(pb2 + 1024);  Q1b = ld16(pb3 + 1024);              // k0+1 t23
      Ab0 = ld16(h1 + ao + 32); Ab1 = ld16(h1 + ao + 32*H1S + 32);  // A k0+1
      MM4_01(Aa0, Aa1, P0a, P0b);                                   // k0 t01
      P0a = ld16(pb0 + 2048);  P0b = ld16(pb1 + 2048);              // k0+2 t01
      MM4_23(Aa0, Aa1, Q0a, Q0b);                                   // k0 t23
      Q0a = ld16(pb2 + 2048);  Q0b = ld16(pb3 + 2048);              // k0+2 t23
      Aa0 = ld16(h1 + ao + 64); Aa1 = ld16(h1 + ao + 32*H1S + 64);  // A k0+2
      MM4_01(Ab0, Ab1, P1a, P1b);                                   // k0+1 t01
      P1a = ld16(pb0 + 3072);  P1b = ld16(pb1 + 3072);              // k0+3 t01
      MM4_23(Ab0, Ab1, Q1a, Q1b);                                   // k0+1 t23
      pb0 += 2048; pb1 += 2048; pb2 += 2048; pb3 += 2048; ao += 64;
    }
    // epilogue: k=62,63 (pointers at k=62; live: P0,Q0=k62, P1=k63, Aa=k62)
    Q1a = ld16(pb2 + 1024);  Q1b = ld16(pb3 + 1024);                // k63 t23
    Ab0 = ld16(h1 + ao + 32); Ab1 = ld16(h1 + ao + 32*H1S + 32);    // A k63
    MM4_01(Aa0, Aa1, P0a, P0b);
    MM4_23(Aa0, Aa1, Q0a, Q0b);
    MM4_01(Ab0, Ab1, P1a, P1b);
    MM4_23(Ab0, Ab1, Q1a, Q1b);
#undef MM4_01
#undef MM4_23
  } else {
    // fallback (no workspace): simple loop with in-flight f32->bf16 conversion
    const int aA0 = l31*H1S + lh*16;
    for (int ks = 0; ks < 64; ++ks){
      bf16x8 A0 = ld16(h1 + aA0 + ks*32);
      bf16x8 A1 = ld16(h1 + aA0 + 32*H1S + ks*32);
      bf16x8 B[4];
#pragma unroll
      for (int nt = 0; nt < 4; ++nt){
        const int col = wid*128 + nt*32 + l31;
        const float* p = W2f + (size_t)col*NEUR + ks*16 + lh*8;
        s16x8 raw;
#pragma unroll
        for (int j = 0; j < 8; ++j) raw[j] = (short)f2bf(p[j]);
        B[nt] = __builtin_bit_cast(bf16x8, raw);
      }
#pragma unroll
      for (int nt = 0; nt < 4; ++nt){
        acc[0][nt] = mfma32(A0, B[nt], acc[0][nt]);
        acc[1][nt] = mfma32(A1, B[nt], acc[1][nt]);
      }
    }
  }
  __syncthreads();   // everyone done reading h1

  // ---- 5. h2 = relu(acc + b2) -> back into h1 (bf16, padded layout)
#pragma unroll
  for (int nt = 0; nt < 4; ++nt){
    const int col = wid*128 + nt*32 + l31;
    const float bv = b2[col];
#pragma unroll
    for (int mt = 0; mt < 2; ++mt)
#pragma unroll
      for (int r = 0; r < 16; ++r){
        const int row = mt*32 + (r & 3) + 8*(r >> 2) + 4*lh;
        *reinterpret_cast<unsigned short*>(h1 + row*H1S + col*2) =
            f2bf(fmaxf(acc[mt][nt][r] + bv, 0.f));
      }
  }
  __syncthreads();

  // ---- 6. GEMM3 (f32 VALU): wave wid owns rows wid*8 .. wid*8+7
  float s[8][3];
#pragma unroll
  for (int rr = 0; rr < 8; ++rr)
#pragma unroll
    for (int j = 0; j < 3; ++j) s[rr][j] = 0.f;

#pragma unroll
  for (int h = 0; h < 2; ++h){
    const int k0 = h*512 + l*8;
    float w3v[3][8];
#pragma unroll
    for (int j = 0; j < 3; ++j)
#pragma unroll
      for (int i = 0; i < 8; ++i) w3v[j][i] = W3[j*NEUR + k0 + i];
#pragma unroll
    for (int rr = 0; rr < 8; ++rr){
      const int row = wid*8 + rr;
      s16x8 raw = *reinterpret_cast<const s16x8*>(h1 + row*H1S + k0*2);
#pragma unroll
      for (int i = 0; i < 8; ++i){
        const float hv = bf2f((unsigned short)raw[i]);
        s[rr][0] += hv * w3v[0][i];
        s[rr][1] += hv * w3v[1][i];
        s[rr][2] += hv * w3v[2][i];
      }
    }
  }
#pragma unroll
  for (int off = 1; off < 64; off <<= 1)
#pragma unroll
    for (int rr = 0; rr < 8; ++rr)
#pragma unroll
      for (int j = 0; j < 3; ++j) s[rr][j] += __shfl_xor(s[rr][j], off, 64);

  if (l == 0){
#pragma unroll
    for (int rr = 0; rr < 8; ++rr){
      const int row = wid*8 + rr;
#pragma unroll
      for (int j = 0; j < 3; ++j)
        out[(rbase + row)*3 + j] = 1.f / (1.f + __expf(-(s[rr][j] + b3[j])));
    }
  }
}

extern "C" void kernel_launch(void* const* d_in, const int* in_sizes, int n_in,
                              void* d_out, int out_size, void* d_ws, size_t ws_size,
                              hipStream_t stream){
  const float* x  = (const float*)d_in[0];
  const float* Wx = (const float*)d_in[1];
  const float* bx = (const float*)d_in[2];
  const float* Wu = (const float*)d_in[3];
  const float* bu = (const float*)d_in[4];
  const float* W1 = (const float*)d_in[5];
  const float* b1 = (const float*)d_in[6];
  const float* W2 = (const float*)d_in[7];
  const float* b2 = (const float*)d_in[8];
  const float* W3 = (const float*)d_in[9];
  const float* b3 = (const float*)d_in[10];
  float* out = (float*)d_out;

  const int batch   = in_sizes[0] / 25;
  const int nblocks = batch / BM;
  const size_t ws_need = (size_t)(32*64*64*8 + 4096*8) * sizeof(unsigned short); // ~2.1 MB
  const int smem = 5120 + BM*H1S;   // 137216 B

  if (ws_size >= ws_need){
    unsigned short* w2opt = (unsigned short*)d_ws;
    unsigned short* w1opt = w2opt + (size_t)32*64*64*8;
    prep_kernel<<<512, 256, 0, stream>>>(W1, W2, w2opt, w1opt);
    hipFuncSetAttribute(reinterpret_cast<const void*>(mlp_kernel<true>),
                        hipFuncAttributeMaxDynamicSharedMemorySize, smem);
    mlp_kernel<true><<<nblocks, THREADS, smem, stream>>>(
        x, Wx, bx, Wu, bu, W1, b1, W2, b2, W3, b3, w2opt, w1opt, out);
  } else {
    hipFuncSetAttribute(reinterpret_cast<const void*>(mlp_kernel<false>),
                        hipFuncAttributeMaxDynamicSharedMemorySize, smem);
    mlp_kernel<false><<<nblocks, THREADS, smem, stream>>>(
        x, Wx, bx, Wu, bu, W1, b1, W2, b2, W3, b3, nullptr, nullptr, out);
  }
}